// Round 3
// baseline (427.973 us; speedup 1.0000x reference)
//
#include <hip/hip_runtime.h>

typedef __attribute__((ext_vector_type(8))) short s16x8;
typedef __attribute__((ext_vector_type(4))) float f32x4;

#define CCH 128

__device__ __forceinline__ ushort f2bf(float f) {
  uint u = __float_as_uint(f);
  u += 0x7fffu + ((u >> 16) & 1u);
  return (ushort)(u >> 16);
}
__device__ __forceinline__ float bf2f(ushort u) {
  return __uint_as_float(((uint)u) << 16);
}

// ======================= NEW PATH (NHWC bf16 copy) =======================

// 2048 blocks (8 b x 256 chunks of 256 px), 256 thr.
// Streams x (NCHW, 1KB contiguous reads), computes per-(b,g) partial stats,
// writes bf16 NHWC copy (4KB contiguous writes) via swizzled LDS transpose.
__global__ __launch_bounds__(256) void pass1_stats_tr(const float* __restrict__ x,
                                                      ushort* __restrict__ xb,
                                                      float2* __restrict__ partials) {
  __shared__ ushort sT[256 * CCH];  // 64 KiB, [px][ch] with 8B-granule XOR swizzle
  __shared__ float ws1[4][8], ws2[4][8];
  const int t = threadIdx.x;
  const int b = blockIdx.x >> 8;
  const int p0 = (blockIdx.x & 255) << 8;
  const int wv = t >> 6, lane = t & 63;
  const int px4 = lane << 2;
  float sg1[8], sg2[8];
#pragma unroll
  for (int g = 0; g < 8; ++g) { sg1[g] = 0.f; sg2[g] = 0.f; }

  const float* xbase = x + (((size_t)b * CCH) << 16) + p0;
#pragma unroll
  for (int i = 0; i < 8; ++i) {
    const int ch = i * 16 + wv * 4;
    float4 v[4];
#pragma unroll
    for (int j = 0; j < 4; ++j)
      v[j] = *(const float4*)(xbase + (((size_t)(ch + j)) << 16) + px4);
#pragma unroll
    for (int j = 0; j < 4; ++j) {
      sg1[i] += v[j].x + v[j].y + v[j].z + v[j].w;
      sg2[i] += v[j].x * v[j].x + v[j].y * v[j].y + v[j].z * v[j].z + v[j].w * v[j].w;
    }
#pragma unroll
    for (int k = 0; k < 4; ++k) {
      const int row = px4 + k;
      const int gs = (i * 4 + wv) ^ (((row >> 3) & 15) << 1);
      ushort4 pk;
      pk.x = f2bf(((const float*)&v[0])[k]);
      pk.y = f2bf(((const float*)&v[1])[k]);
      pk.z = f2bf(((const float*)&v[2])[k]);
      pk.w = f2bf(((const float*)&v[3])[k]);
      *(ushort4*)&sT[row * CCH + gs * 4] = pk;
    }
  }
  // block-level stats partials
#pragma unroll
  for (int g = 0; g < 8; ++g) {
    float a = sg1[g], q = sg2[g];
#pragma unroll
    for (int off = 32; off > 0; off >>= 1) {
      a += __shfl_down(a, off);
      q += __shfl_down(q, off);
    }
    if (lane == 0) { ws1[wv][g] = a; ws2[wv][g] = q; }
  }
  __syncthreads();
  if (t < 8) {
    float a = ws1[0][t] + ws1[1][t] + ws1[2][t] + ws1[3][t];
    float q = ws2[0][t] + ws2[1][t] + ws2[2][t] + ws2[3][t];
    partials[blockIdx.x * 8 + t] = (float2){a, q};
  }
  // phase B: NHWC write, 1KB contiguous per wave-instruction
  const int c16 = t & 15, pr = t >> 4;
  ushort* dst = xb + ((size_t)((b << 16) + p0)) * CCH;
#pragma unroll
  for (int s = 0; s < 16; ++s) {
    const int row = s * 16 + pr;
    const int gs = (c16 * 2) ^ (((row >> 3) & 15) << 1);
    *(s16x8*)&dst[(size_t)row * CCH + c16 * 8] = *(const s16x8*)&sT[row * CCH + gs * 4];
  }
}

// 64 threads: one per (b,g); sum 256 chunk-partials, emit per-(b,c) scale/shift.
__global__ void stats_finalize2(const float2* __restrict__ partials,
                                const float* __restrict__ gn_w,
                                const float* __restrict__ gn_b,
                                float* __restrict__ scale, float* __restrict__ shift) {
  const int t = threadIdx.x;
  const int b = t >> 3, g = t & 7;
  float s1 = 0.f, s2 = 0.f;
  for (int c = 0; c < 256; ++c) {
    float2 p = partials[(b * 256 + c) * 8 + g];
    s1 += p.x;
    s2 += p.y;
  }
  const float invN = 1.0f / 1048576.0f;
  const float mean = s1 * invN;
  const float var = s2 * invN - mean * mean;
  const float rstd = rsqrtf(var + 1e-5f);
  for (int i = 0; i < 16; ++i) {
    const int c = g * 16 + i;
    const float sc = rstd * gn_w[c];
    scale[b * CCH + c] = sc;
    shift[b * CCH + c] = gn_b[c] - mean * sc;
  }
}

__global__ __launch_bounds__(256) void prep_w2(const float* __restrict__ w2,
                                               ushort* __restrict__ w2b) {
  int i = blockIdx.x * 256 + threadIdx.x;
  float4 a = ((const float4*)w2)[i];
  ushort4 o;
  o.x = f2bf(a.x); o.y = f2bf(a.y); o.z = f2bf(a.z); o.w = f2bf(a.w);
  ((ushort4*)w2b)[i] = o;
}

// W1'[b][o][c] = w1[o][c]*scale[b][c] (bf16); c1[b][o] = w1[o,:].shift[b,:] + b1[o]
__global__ __launch_bounds__(128) void fold_w1(const float* __restrict__ w1,
                                               const float* __restrict__ b1,
                                               const float* __restrict__ scale,
                                               const float* __restrict__ shift,
                                               ushort* __restrict__ W1b,
                                               float* __restrict__ c1) {
  const int b = blockIdx.x >> 7, o = blockIdx.x & 127, c = threadIdx.x;
  const float wv = w1[o * CCH + c];
  W1b[(b << 14) + o * CCH + c] = f2bf(wv * scale[b * CCH + c]);
  float s = wv * shift[b * CCH + c];
#pragma unroll
  for (int off = 32; off > 0; off >>= 1) s += __shfl_down(s, off);
  __shared__ float tmp[2];
  if ((threadIdx.x & 63) == 0) tmp[threadIdx.x >> 6] = s;
  __syncthreads();
  if (threadIdx.x == 0) c1[(b << 7) + o] = tmp[0] + tmp[1] + b1[o];
}

// 4096 blocks (8 b x 512 chunks of 128 px), 256 thr = 4 INDEPENDENT waves.
// No barriers. B-frags + residual direct from NHWC bf16 (contiguous, L3-hot);
// weights from L2; H redistributed through wave-private 4 KiB LDS slice.
__global__ __launch_bounds__(256) void pass2_mlp(
    const ushort* __restrict__ xb, const ushort* __restrict__ W1b,
    const ushort* __restrict__ w2b, const float* __restrict__ c1,
    const float* __restrict__ b2, float* __restrict__ out) {
  __shared__ ushort hT[4][16 * CCH];  // 16 KiB total
  const int t = threadIdx.x;
  const int wv = t >> 6, lane = t & 63;
  const int fl = lane & 15, fh = lane >> 4;
  const int b = blockIdx.x >> 9;
  const int p0 = ((blockIdx.x & 511) << 7) + wv * 32;
  const ushort* xrow = xb + ((size_t)((b << 16) + p0)) * CCH;
  const ushort* w1p = W1b + (b << 14);
  const float* c1b = c1 + (b << 7);
  ushort* hw = &hT[wv][0];

#pragma unroll
  for (int tp = 0; tp < 2; ++tp) {
    const ushort* xt = xrow + (tp * 16 + fl) * CCH;
    // ---- GEMM1: acc = W1' . x ----
    f32x4 acc[8];
#pragma unroll
    for (int to = 0; to < 8; ++to) acc[to] = (f32x4){0.f, 0.f, 0.f, 0.f};
#pragma unroll
    for (int k0 = 0; k0 < 4; ++k0) {
      const int kb = k0 * 32 + fh * 8;
      const s16x8 bt = *(const s16x8*)&xt[kb];
#pragma unroll
      for (int to = 0; to < 8; ++to) {
        const s16x8 a = *(const s16x8*)&w1p[(to * 16 + fl) * CCH + kb];
        acc[to] = __builtin_amdgcn_mfma_f32_16x16x32_bf16(a, bt, acc[to], 0, 0, 0);
      }
    }
    // ---- H = relu(acc + c1) -> wave-private LDS (program-order safe) ----
#pragma unroll
    for (int to = 0; to < 8; ++to) {
      const float4 cc = *(const float4*)&c1b[to * 16 + fh * 4];
      ushort4 pk;
      pk.x = f2bf(fmaxf(acc[to][0] + cc.x, 0.f));
      pk.y = f2bf(fmaxf(acc[to][1] + cc.y, 0.f));
      pk.z = f2bf(fmaxf(acc[to][2] + cc.z, 0.f));
      pk.w = f2bf(fmaxf(acc[to][3] + cc.w, 0.f));
      const int gs = (to * 4 + fh) ^ (fl << 1);
      *(ushort4*)&hw[fl * CCH + gs * 4] = pk;
    }
    // ---- GEMM2: acc2 = w2 . H ----
    f32x4 acc2[8];
#pragma unroll
    for (int to = 0; to < 8; ++to) acc2[to] = (f32x4){0.f, 0.f, 0.f, 0.f};
#pragma unroll
    for (int k0 = 0; k0 < 4; ++k0) {
      const int kb = k0 * 32 + fh * 8;
      const int gs = (k0 * 8 + fh * 2) ^ (fl << 1);
      const s16x8 bt = *(const s16x8*)&hw[fl * CCH + gs * 4];
#pragma unroll
      for (int to = 0; to < 8; ++to) {
        const s16x8 a = *(const s16x8*)&w2b[(to * 16 + fl) * CCH + kb];
        acc2[to] = __builtin_amdgcn_mfma_f32_16x16x32_bf16(a, bt, acc2[to], 0, 0, 0);
      }
    }
    // ---- epilogue: out = x + ffn + b2 (residual from L1-hot NHWC bf16) ----
#pragma unroll
    for (int to = 0; to < 8; ++to) {
      const int ob = to * 16 + fh * 4;
      const float4 bb = *(const float4*)&b2[ob];
      const ushort4 rx = *(const ushort4*)&xt[ob];
      const float rxf[4] = {bf2f(rx.x), bf2f(rx.y), bf2f(rx.z), bf2f(rx.w)};
#pragma unroll
      for (int r = 0; r < 4; ++r) {
        const size_t idx = (((size_t)(b * CCH + ob + r)) << 16) + p0 + tp * 16 + fl;
        out[idx] = rxf[r] + acc2[to][r] + ((const float*)&bb)[r];
      }
    }
  }
}

// ======================= FALLBACK PATH (round-1, proven) =======================

__device__ __forceinline__ int swz(int row, int col) {
  return (row << 7) | (col ^ ((row & 7) << 3));
}

__global__ __launch_bounds__(256) void prep_weights_fb(const float* __restrict__ w1,
                                                       const float* __restrict__ w2,
                                                       ushort* __restrict__ w1b,
                                                       ushort* __restrict__ w2b) {
  int i = blockIdx.x * 256 + threadIdx.x;
  float4 a = ((const float4*)w1)[i];
  ushort4 oa;
  oa.x = f2bf(a.x); oa.y = f2bf(a.y); oa.z = f2bf(a.z); oa.w = f2bf(a.w);
  ((ushort4*)w1b)[i] = oa;
  float4 bq = ((const float4*)w2)[i];
  ushort4 ob;
  ob.x = f2bf(bq.x); ob.y = f2bf(bq.y); ob.z = f2bf(bq.z); ob.w = f2bf(bq.w);
  ((ushort4*)w2b)[i] = ob;
}

__global__ __launch_bounds__(256) void stats_partial_fb(const float* __restrict__ x,
                                                        float* __restrict__ partials) {
  const float4* xp = (const float4*)(x + ((size_t)blockIdx.x << 16));
  const int tid = threadIdx.x;
  float s1 = 0.f, s2 = 0.f;
#pragma unroll 8
  for (int i = 0; i < 64; ++i) {
    float4 v = xp[i * 256 + tid];
    s1 += v.x + v.y + v.z + v.w;
    s2 += v.x * v.x + v.y * v.y + v.z * v.z + v.w * v.w;
  }
#pragma unroll
  for (int off = 32; off > 0; off >>= 1) {
    s1 += __shfl_down(s1, off);
    s2 += __shfl_down(s2, off);
  }
  __shared__ float r1[4], r2[4];
  const int wv = tid >> 6;
  if ((tid & 63) == 0) { r1[wv] = s1; r2[wv] = s2; }
  __syncthreads();
  if (tid == 0) {
    partials[blockIdx.x * 2] = r1[0] + r1[1] + r1[2] + r1[3];
    partials[blockIdx.x * 2 + 1] = r2[0] + r2[1] + r2[2] + r2[3];
  }
}

__global__ void stats_finalize_fb(const float* __restrict__ partials,
                                  const float* __restrict__ gn_w,
                                  const float* __restrict__ gn_b,
                                  float* __restrict__ scale, float* __restrict__ shift) {
  const int t = threadIdx.x;
  float s1 = 0.f, s2 = 0.f;
#pragma unroll
  for (int i = 0; i < 16; ++i) {
    s1 += partials[(t * 16 + i) * 2];
    s2 += partials[(t * 16 + i) * 2 + 1];
  }
  const float invN = 1.0f / 1048576.0f;
  const float mean = s1 * invN;
  const float var = s2 * invN - mean * mean;
  const float rstd = rsqrtf(var + 1e-5f);
  const int b = t >> 3, g = t & 7;
  for (int i = 0; i < 16; ++i) {
    const int c = g * 16 + i;
    const float sc = rstd * gn_w[c];
    scale[b * CCH + c] = sc;
    shift[b * CCH + c] = gn_b[c] - mean * sc;
  }
}

__global__ __launch_bounds__(256) void fused_main_fb(
    const float* __restrict__ x, const ushort* __restrict__ w1b,
    const ushort* __restrict__ w2b, const float* __restrict__ scale,
    const float* __restrict__ shift, const float* __restrict__ b1,
    const float* __restrict__ b2, float* __restrict__ out) {
  __shared__ ushort sB[128 * 128];
  const int tid = threadIdx.x;
  const int b = blockIdx.x >> 9;
  const int p0 = (blockIdx.x & 511) << 7;
  const int lane = tid & 63;
  const int wv = tid >> 6;
  const int fl = lane & 15;
  const int fh = lane >> 4;
  {
    const int p = tid & 127;
    const int ch0 = (tid >> 7) << 6;
    const float* xbp = x + (((size_t)b * CCH) << 16) + p0 + p;
    const float* scb = scale + b * CCH;
    const float* shb = shift + b * CCH;
#pragma unroll
    for (int cc = 0; cc < 64; cc += 16) {
      float v[16];
#pragma unroll
      for (int i = 0; i < 16; ++i) v[i] = xbp[((size_t)(ch0 + cc + i)) << 16];
#pragma unroll
      for (int q = 0; q < 4; ++q) {
        const int c = ch0 + cc + q * 4;
        ushort4 pk;
        pk.x = f2bf(v[q * 4 + 0] * scb[c + 0] + shb[c + 0]);
        pk.y = f2bf(v[q * 4 + 1] * scb[c + 1] + shb[c + 1]);
        pk.z = f2bf(v[q * 4 + 2] * scb[c + 2] + shb[c + 2]);
        pk.w = f2bf(v[q * 4 + 3] * scb[c + 3] + shb[c + 3]);
        *(ushort4*)&sB[swz(p, c)] = pk;
      }
    }
  }
  __syncthreads();
  f32x4 acc[2][8];
#pragma unroll
  for (int f = 0; f < 2; ++f)
#pragma unroll
    for (int j = 0; j < 8; ++j) acc[f][j] = (f32x4){0.f, 0.f, 0.f, 0.f};
#pragma unroll
  for (int k0 = 0; k0 < 128; k0 += 32) {
    const int kb = k0 + fh * 8;
    const s16x8 a0 = *(const s16x8*)(w1b + (wv * 32 + fl) * CCH + kb);
    const s16x8 a1 = *(const s16x8*)(w1b + (wv * 32 + 16 + fl) * CCH + kb);
#pragma unroll
    for (int j = 0; j < 8; ++j) {
      const s16x8 bf = *(const s16x8*)&sB[swz(j * 16 + fl, kb)];
      acc[0][j] = __builtin_amdgcn_mfma_f32_16x16x32_bf16(a0, bf, acc[0][j], 0, 0, 0);
      acc[1][j] = __builtin_amdgcn_mfma_f32_16x16x32_bf16(a1, bf, acc[1][j], 0, 0, 0);
    }
  }
  __syncthreads();
#pragma unroll
  for (int f = 0; f < 2; ++f) {
    const int ob = wv * 32 + f * 16 + fh * 4;
    float bb[4];
#pragma unroll
    for (int r = 0; r < 4; ++r) bb[r] = b1[ob + r];
#pragma unroll
    for (int j = 0; j < 8; ++j) {
      const int pcol = j * 16 + fl;
      ushort4 pk;
      pk.x = f2bf(fmaxf(acc[f][j][0] + bb[0], 0.f));
      pk.y = f2bf(fmaxf(acc[f][j][1] + bb[1], 0.f));
      pk.z = f2bf(fmaxf(acc[f][j][2] + bb[2], 0.f));
      pk.w = f2bf(fmaxf(acc[f][j][3] + bb[3], 0.f));
      *(ushort4*)&sB[swz(pcol, ob)] = pk;
    }
  }
  __syncthreads();
  f32x4 acc2[2][8];
#pragma unroll
  for (int f = 0; f < 2; ++f)
#pragma unroll
    for (int j = 0; j < 8; ++j) acc2[f][j] = (f32x4){0.f, 0.f, 0.f, 0.f};
#pragma unroll
  for (int k0 = 0; k0 < 128; k0 += 32) {
    const int kb = k0 + fh * 8;
    const s16x8 a0 = *(const s16x8*)(w2b + (wv * 32 + fl) * CCH + kb);
    const s16x8 a1 = *(const s16x8*)(w2b + (wv * 32 + 16 + fl) * CCH + kb);
#pragma unroll
    for (int j = 0; j < 8; ++j) {
      const s16x8 bf = *(const s16x8*)&sB[swz(j * 16 + fl, kb)];
      acc2[0][j] = __builtin_amdgcn_mfma_f32_16x16x32_bf16(a0, bf, acc2[0][j], 0, 0, 0);
      acc2[1][j] = __builtin_amdgcn_mfma_f32_16x16x32_bf16(a1, bf, acc2[1][j], 0, 0, 0);
    }
  }
#pragma unroll
  for (int f = 0; f < 2; ++f) {
    const int ob = wv * 32 + f * 16 + fh * 4;
    float bb[4];
#pragma unroll
    for (int r = 0; r < 4; ++r) bb[r] = b2[ob + r];
#pragma unroll
    for (int j = 0; j < 8; ++j) {
      const int pcol = p0 + j * 16 + fl;
      const size_t base = (((size_t)(b * CCH + ob)) << 16) + pcol;
#pragma unroll
      for (int r = 0; r < 4; ++r) {
        const size_t idx = base + ((size_t)r << 16);
        out[idx] = x[idx] + acc2[f][j][r] + bb[r];
      }
    }
  }
}

// ======================= launcher =======================

extern "C" void kernel_launch(void* const* d_in, const int* in_sizes, int n_in,
                              void* d_out, int out_size, void* d_ws, size_t ws_size,
                              hipStream_t stream) {
  const float* x    = (const float*)d_in[0];
  const float* gn_w = (const float*)d_in[1];
  const float* gn_b = (const float*)d_in[2];
  const float* w1   = (const float*)d_in[3];
  const float* b1   = (const float*)d_in[4];
  const float* w2   = (const float*)d_in[5];
  const float* b2   = (const float*)d_in[6];
  float* out = (float*)d_out;
  char* ws = (char*)d_ws;

  const size_t XB_BYTES = (size_t)8 * 65536 * CCH * 2;  // 128 MiB
  const size_t NEED = XB_BYTES + 131072 + 4096 + 4096 + 32768 + 262144 + 4096;

  if (ws_size >= NEED) {
    ushort* xbuf    = (ushort*)ws;
    float2* parts   = (float2*)(ws + XB_BYTES);
    float* scale    = (float*)(ws + XB_BYTES + 131072);
    float* shift    = (float*)(ws + XB_BYTES + 135168);
    ushort* w2b     = (ushort*)(ws + XB_BYTES + 139264);
    ushort* W1b     = (ushort*)(ws + XB_BYTES + 172032);
    float* c1       = (float*)(ws + XB_BYTES + 434176);

    hipLaunchKernelGGL(pass1_stats_tr, dim3(2048), dim3(256), 0, stream, x, xbuf, parts);
    hipLaunchKernelGGL(prep_w2, dim3(16), dim3(256), 0, stream, w2, w2b);
    hipLaunchKernelGGL(stats_finalize2, dim3(1), dim3(64), 0, stream, parts, gn_w, gn_b, scale, shift);
    hipLaunchKernelGGL(fold_w1, dim3(1024), dim3(128), 0, stream, w1, b1, scale, shift, W1b, c1);
    hipLaunchKernelGGL(pass2_mlp, dim3(4096), dim3(256), 0, stream, xbuf, W1b, w2b, c1, b2, out);
  } else {
    float* partials = (float*)ws;
    float* scale    = (float*)(ws + 8192);
    float* shift    = (float*)(ws + 12288);
    ushort* w1b     = (ushort*)(ws + 16384);
    ushort* w2b     = (ushort*)(ws + 49152);

    hipLaunchKernelGGL(prep_weights_fb, dim3(16), dim3(256), 0, stream, w1, w2, w1b, w2b);
    hipLaunchKernelGGL(stats_partial_fb, dim3(1024), dim3(256), 0, stream, x, partials);
    hipLaunchKernelGGL(stats_finalize_fb, dim3(1), dim3(64), 0, stream, partials, gn_w, gn_b, scale, shift);
    hipLaunchKernelGGL(fused_main_fb, dim3(4096), dim3(256), 0, stream, x, w1b, w2b, scale, shift, b1, b2, out);
  }
}

// Round 4
// 233.953 us; speedup vs baseline: 1.8293x; 1.8293x over previous
//
#include <hip/hip_runtime.h>

typedef __attribute__((ext_vector_type(8))) short s16x8;
typedef __attribute__((ext_vector_type(4))) float f32x4;

#define CCH 128

__device__ __forceinline__ ushort f2bf(float f) {
  uint u = __float_as_uint(f);
  u += 0x7fffu + ((u >> 16) & 1u);
  return (ushort)(u >> 16);
}
__device__ __forceinline__ float bf2f(ushort u) {
  return __uint_as_float(((uint)u) << 16);
}

// swizzled byte-ish index into a [row][128] bf16 LDS tile (col in elements)
__device__ __forceinline__ int swz(int row, int col) {
  return (row << 7) | (col ^ ((row & 7) << 3));
}

// ---------- pass1: stats + NCHW fp32 -> NHWC bf16 transpose copy (proven r3) ----------
// 2048 blocks (8 b x 256 chunks of 256 px), 256 thr.
__global__ __launch_bounds__(256) void pass1_stats_tr(const float* __restrict__ x,
                                                      ushort* __restrict__ xb,
                                                      float2* __restrict__ partials) {
  __shared__ ushort sT[256 * CCH];  // 64 KiB, [px][ch], 8B-granule XOR swizzle
  __shared__ float ws1[4][8], ws2[4][8];
  const int t = threadIdx.x;
  const int b = blockIdx.x >> 8;
  const int p0 = (blockIdx.x & 255) << 8;
  const int wv = t >> 6, lane = t & 63;
  const int px4 = lane << 2;
  float sg1[8], sg2[8];
#pragma unroll
  for (int g = 0; g < 8; ++g) { sg1[g] = 0.f; sg2[g] = 0.f; }

  const float* xbase = x + (((size_t)b * CCH) << 16) + p0;
#pragma unroll
  for (int i = 0; i < 8; ++i) {
    const int ch = i * 16 + wv * 4;
    float4 v[4];
#pragma unroll
    for (int j = 0; j < 4; ++j)
      v[j] = *(const float4*)(xbase + (((size_t)(ch + j)) << 16) + px4);
#pragma unroll
    for (int j = 0; j < 4; ++j) {
      sg1[i] += v[j].x + v[j].y + v[j].z + v[j].w;
      sg2[i] += v[j].x * v[j].x + v[j].y * v[j].y + v[j].z * v[j].z + v[j].w * v[j].w;
    }
#pragma unroll
    for (int k = 0; k < 4; ++k) {
      const int row = px4 + k;
      const int gs = (i * 4 + wv) ^ (((row >> 3) & 15) << 1);
      ushort4 pk;
      pk.x = f2bf(((const float*)&v[0])[k]);
      pk.y = f2bf(((const float*)&v[1])[k]);
      pk.z = f2bf(((const float*)&v[2])[k]);
      pk.w = f2bf(((const float*)&v[3])[k]);
      *(ushort4*)&sT[row * CCH + gs * 4] = pk;
    }
  }
#pragma unroll
  for (int g = 0; g < 8; ++g) {
    float a = sg1[g], q = sg2[g];
#pragma unroll
    for (int off = 32; off > 0; off >>= 1) {
      a += __shfl_down(a, off);
      q += __shfl_down(q, off);
    }
    if (lane == 0) { ws1[wv][g] = a; ws2[wv][g] = q; }
  }
  __syncthreads();
  if (t < 8) {
    float a = ws1[0][t] + ws1[1][t] + ws1[2][t] + ws1[3][t];
    float q = ws2[0][t] + ws2[1][t] + ws2[2][t] + ws2[3][t];
    partials[blockIdx.x * 8 + t] = (float2){a, q};
  }
  const int c16 = t & 15, pr = t >> 4;
  ushort* dst = xb + ((size_t)((b << 16) + p0)) * CCH;
#pragma unroll
  for (int s = 0; s < 16; ++s) {
    const int row = s * 16 + pr;
    const int gs = (c16 * 2) ^ (((row >> 3) & 15) << 1);
    *(s16x8*)&dst[(size_t)row * CCH + c16 * 8] = *(const s16x8*)&sT[row * CCH + gs * 4];
  }
}

// ---------- finalize + weight prep (proven r2/r3) ----------
__global__ void stats_finalize2(const float2* __restrict__ partials,
                                const float* __restrict__ gn_w,
                                const float* __restrict__ gn_b,
                                float* __restrict__ scale, float* __restrict__ shift) {
  const int t = threadIdx.x;
  const int b = t >> 3, g = t & 7;
  float s1 = 0.f, s2 = 0.f;
  for (int c = 0; c < 256; ++c) {
    float2 p = partials[(b * 256 + c) * 8 + g];
    s1 += p.x;
    s2 += p.y;
  }
  const float invN = 1.0f / 1048576.0f;
  const float mean = s1 * invN;
  const float var = s2 * invN - mean * mean;
  const float rstd = rsqrtf(var + 1e-5f);
  for (int i = 0; i < 16; ++i) {
    const int c = g * 16 + i;
    const float sc = rstd * gn_w[c];
    scale[b * CCH + c] = sc;
    shift[b * CCH + c] = gn_b[c] - mean * sc;
  }
}

__global__ __launch_bounds__(256) void prep_w2(const float* __restrict__ w2,
                                               ushort* __restrict__ w2b) {
  int i = blockIdx.x * 256 + threadIdx.x;
  float4 a = ((const float4*)w2)[i];
  ushort4 o;
  o.x = f2bf(a.x); o.y = f2bf(a.y); o.z = f2bf(a.z); o.w = f2bf(a.w);
  ((ushort4*)w2b)[i] = o;
}

// W1'[b][o][c] = w1[o][c]*scale[b][c] (bf16); c1[b][o] = w1[o,:].shift[b,:] + b1[o]
__global__ __launch_bounds__(128) void fold_w1(const float* __restrict__ w1,
                                               const float* __restrict__ b1,
                                               const float* __restrict__ scale,
                                               const float* __restrict__ shift,
                                               ushort* __restrict__ W1b,
                                               float* __restrict__ c1) {
  const int b = blockIdx.x >> 7, o = blockIdx.x & 127, c = threadIdx.x;
  const float wv = w1[o * CCH + c];
  W1b[(b << 14) + o * CCH + c] = f2bf(wv * scale[b * CCH + c]);
  float s = wv * shift[b * CCH + c];
#pragma unroll
  for (int off = 32; off > 0; off >>= 1) s += __shfl_down(s, off);
  __shared__ float tmp[2];
  if ((threadIdx.x & 63) == 0) tmp[threadIdx.x >> 6] = s;
  __syncthreads();
  if (threadIdx.x == 0) c1[(b << 7) + o] = tmp[0] + tmp[1] + b1[o];
}

// ---------- pass2: round-1 cooperative skeleton, NHWC-fed stage ----------
// 4096 blocks (8 b x 512 tiles of 128 px), 256 thr = 4 waves, 32 KiB LDS.
__global__ __launch_bounds__(256, 4) void mlp_tiled(
    const ushort* __restrict__ xb, const ushort* __restrict__ W1b,
    const ushort* __restrict__ w2b, const float* __restrict__ c1,
    const float* __restrict__ b2, float* __restrict__ out) {
  __shared__ ushort sB[128 * CCH];  // 32 KiB, [px][ch] swizzled; reused for H
  const int t = threadIdx.x;
  const int b = blockIdx.x >> 9;
  const int p0 = (blockIdx.x & 511) << 7;
  const int lane = t & 63;
  const int wv = t >> 6;
  const int fl = lane & 15;
  const int fh = lane >> 4;

  // ---- stage: NHWC bf16 global -> swizzled LDS (pure vector copy) ----
  const ushort* src = xb + ((size_t)((b << 16) + p0)) * CCH;
#pragma unroll
  for (int i = 0; i < 8; ++i) {
    const int u = i * 256 + t;      // 16B-unit index within the 32 KiB tile
    const int px = u >> 4;
    const int ch = (u & 15) * 8;
    const s16x8 v = *(const s16x8*)(src + px * CCH + ch);
    *(s16x8*)&sB[swz(px, ch)] = v;
  }
  __syncthreads();

  // ---- GEMM1: H = W1' . x  (A from L2 weights, B from LDS) ----
  f32x4 acc[2][8];
#pragma unroll
  for (int f = 0; f < 2; ++f)
#pragma unroll
    for (int j = 0; j < 8; ++j) acc[f][j] = (f32x4){0.f, 0.f, 0.f, 0.f};

  const ushort* w1p = W1b + (b << 14);
#pragma unroll
  for (int k0 = 0; k0 < 128; k0 += 32) {
    const int kb = k0 + fh * 8;
    const s16x8 a0 = *(const s16x8*)(w1p + (wv * 32 + fl) * CCH + kb);
    const s16x8 a1 = *(const s16x8*)(w1p + (wv * 32 + 16 + fl) * CCH + kb);
#pragma unroll
    for (int j = 0; j < 8; ++j) {
      const s16x8 bf = *(const s16x8*)&sB[swz(j * 16 + fl, kb)];
      acc[0][j] = __builtin_amdgcn_mfma_f32_16x16x32_bf16(a0, bf, acc[0][j], 0, 0, 0);
      acc[1][j] = __builtin_amdgcn_mfma_f32_16x16x32_bf16(a1, bf, acc[1][j], 0, 0, 0);
    }
  }
  __syncthreads();  // all sB reads done before overwrite

  // ---- writeback: H = relu(acc + c1) -> sB ----
  const float* c1b = c1 + (b << 7);
#pragma unroll
  for (int f = 0; f < 2; ++f) {
    const int ob = wv * 32 + f * 16 + fh * 4;
    const float4 cc = *(const float4*)(c1b + ob);
#pragma unroll
    for (int j = 0; j < 8; ++j) {
      ushort4 pk;
      pk.x = f2bf(fmaxf(acc[f][j][0] + cc.x, 0.f));
      pk.y = f2bf(fmaxf(acc[f][j][1] + cc.y, 0.f));
      pk.z = f2bf(fmaxf(acc[f][j][2] + cc.z, 0.f));
      pk.w = f2bf(fmaxf(acc[f][j][3] + cc.w, 0.f));
      *(ushort4*)&sB[swz(j * 16 + fl, ob)] = pk;
    }
  }
  __syncthreads();

  // ---- GEMM2: ffn = w2 . H ----
  f32x4 acc2[2][8];
#pragma unroll
  for (int f = 0; f < 2; ++f)
#pragma unroll
    for (int j = 0; j < 8; ++j) acc2[f][j] = (f32x4){0.f, 0.f, 0.f, 0.f};

#pragma unroll
  for (int k0 = 0; k0 < 128; k0 += 32) {
    const int kb = k0 + fh * 8;
    const s16x8 a0 = *(const s16x8*)(w2b + (wv * 32 + fl) * CCH + kb);
    const s16x8 a1 = *(const s16x8*)(w2b + (wv * 32 + 16 + fl) * CCH + kb);
#pragma unroll
    for (int j = 0; j < 8; ++j) {
      const s16x8 bf = *(const s16x8*)&sB[swz(j * 16 + fl, kb)];
      acc2[0][j] = __builtin_amdgcn_mfma_f32_16x16x32_bf16(a0, bf, acc2[0][j], 0, 0, 0);
      acc2[1][j] = __builtin_amdgcn_mfma_f32_16x16x32_bf16(a1, bf, acc2[1][j], 0, 0, 0);
    }
  }

  // ---- epilogue: out = x + ffn + b2 (residual from L1/L2-hot NHWC bf16) ----
#pragma unroll
  for (int f = 0; f < 2; ++f) {
    const int ob = wv * 32 + f * 16 + fh * 4;
    const float4 bb = *(const float4*)(b2 + ob);
#pragma unroll
    for (int j = 0; j < 8; ++j) {
      const int pcol = j * 16 + fl;
      const ushort4 rx = *(const ushort4*)(src + pcol * CCH + ob);
      const size_t base = (((size_t)(b * CCH + ob)) << 16) + p0 + pcol;
      out[base] = bf2f(rx.x) + acc2[f][j][0] + bb.x;
      out[base + ((size_t)1 << 16)] = bf2f(rx.y) + acc2[f][j][1] + bb.y;
      out[base + ((size_t)2 << 16)] = bf2f(rx.z) + acc2[f][j][2] + bb.z;
      out[base + ((size_t)3 << 16)] = bf2f(rx.w) + acc2[f][j][3] + bb.w;
    }
  }
}

// ---------- launcher ----------
extern "C" void kernel_launch(void* const* d_in, const int* in_sizes, int n_in,
                              void* d_out, int out_size, void* d_ws, size_t ws_size,
                              hipStream_t stream) {
  const float* x    = (const float*)d_in[0];
  const float* gn_w = (const float*)d_in[1];
  const float* gn_b = (const float*)d_in[2];
  const float* w1   = (const float*)d_in[3];
  const float* b1   = (const float*)d_in[4];
  const float* w2   = (const float*)d_in[5];
  const float* b2   = (const float*)d_in[6];
  float* out = (float*)d_out;
  char* ws = (char*)d_ws;

  const size_t XB_BYTES = (size_t)8 * 65536 * CCH * 2;  // 128 MiB
  ushort* xbuf  = (ushort*)ws;
  float2* parts = (float2*)(ws + XB_BYTES);
  float* scale  = (float*)(ws + XB_BYTES + 131072);
  float* shift  = (float*)(ws + XB_BYTES + 135168);
  ushort* w2b   = (ushort*)(ws + XB_BYTES + 139264);
  ushort* W1b   = (ushort*)(ws + XB_BYTES + 172032);
  float* c1     = (float*)(ws + XB_BYTES + 434176);

  hipLaunchKernelGGL(pass1_stats_tr, dim3(2048), dim3(256), 0, stream, x, xbuf, parts);
  hipLaunchKernelGGL(prep_w2, dim3(16), dim3(256), 0, stream, w2, w2b);
  hipLaunchKernelGGL(stats_finalize2, dim3(1), dim3(64), 0, stream, parts, gn_w, gn_b, scale, shift);
  hipLaunchKernelGGL(fold_w1, dim3(1024), dim3(128), 0, stream, w1, b1, scale, shift, W1b, c1);
  hipLaunchKernelGGL(mlp_tiled, dim3(4096), dim3(256), 0, stream, xbuf, W1b, w2b, c1, b2, out);
}

// Round 5
// 218.140 us; speedup vs baseline: 1.9619x; 1.0725x over previous
//
#include <hip/hip_runtime.h>

typedef __attribute__((ext_vector_type(8))) short s16x8;
typedef __attribute__((ext_vector_type(4))) float f32x4;

#define CCH 128

__device__ __forceinline__ ushort f2bf(float f) {
  uint u = __float_as_uint(f);
  u += 0x7fffu + ((u >> 16) & 1u);
  return (ushort)(u >> 16);
}
__device__ __forceinline__ float bf2f(ushort u) {
  return __uint_as_float(((uint)u) << 16);
}

// swizzled index into a [row][128] bf16 LDS tile (col in elements)
__device__ __forceinline__ int swz(int row, int col) {
  return (row << 7) | (col ^ ((row & 7) << 3));
}

// ---------- pass1: stats + NCHW fp32 -> NHWC bf16 transpose copy (proven) ----------
__global__ __launch_bounds__(256) void pass1_stats_tr(const float* __restrict__ x,
                                                      ushort* __restrict__ xb,
                                                      float2* __restrict__ partials) {
  __shared__ ushort sT[256 * CCH];  // 64 KiB, [px][ch], 8B-granule XOR swizzle
  __shared__ float ws1[4][8], ws2[4][8];
  const int t = threadIdx.x;
  const int b = blockIdx.x >> 8;
  const int p0 = (blockIdx.x & 255) << 8;
  const int wv = t >> 6, lane = t & 63;
  const int px4 = lane << 2;
  float sg1[8], sg2[8];
#pragma unroll
  for (int g = 0; g < 8; ++g) { sg1[g] = 0.f; sg2[g] = 0.f; }

  const float* xbase = x + (((size_t)b * CCH) << 16) + p0;
#pragma unroll
  for (int i = 0; i < 8; ++i) {
    const int ch = i * 16 + wv * 4;
    float4 v[4];
#pragma unroll
    for (int j = 0; j < 4; ++j)
      v[j] = *(const float4*)(xbase + (((size_t)(ch + j)) << 16) + px4);
#pragma unroll
    for (int j = 0; j < 4; ++j) {
      sg1[i] += v[j].x + v[j].y + v[j].z + v[j].w;
      sg2[i] += v[j].x * v[j].x + v[j].y * v[j].y + v[j].z * v[j].z + v[j].w * v[j].w;
    }
#pragma unroll
    for (int k = 0; k < 4; ++k) {
      const int row = px4 + k;
      const int gs = (i * 4 + wv) ^ (((row >> 3) & 15) << 1);
      ushort4 pk;
      pk.x = f2bf(((const float*)&v[0])[k]);
      pk.y = f2bf(((const float*)&v[1])[k]);
      pk.z = f2bf(((const float*)&v[2])[k]);
      pk.w = f2bf(((const float*)&v[3])[k]);
      *(ushort4*)&sT[row * CCH + gs * 4] = pk;
    }
  }
#pragma unroll
  for (int g = 0; g < 8; ++g) {
    float a = sg1[g], q = sg2[g];
#pragma unroll
    for (int off = 32; off > 0; off >>= 1) {
      a += __shfl_down(a, off);
      q += __shfl_down(q, off);
    }
    if (lane == 0) { ws1[wv][g] = a; ws2[wv][g] = q; }
  }
  __syncthreads();
  if (t < 8) {
    float a = ws1[0][t] + ws1[1][t] + ws1[2][t] + ws1[3][t];
    float q = ws2[0][t] + ws2[1][t] + ws2[2][t] + ws2[3][t];
    partials[blockIdx.x * 8 + t] = (float2){a, q};
  }
  const int c16 = t & 15, pr = t >> 4;
  ushort* dst = xb + ((size_t)((b << 16) + p0)) * CCH;
#pragma unroll
  for (int s = 0; s < 16; ++s) {
    const int row = s * 16 + pr;
    const int gs = (c16 * 2) ^ (((row >> 3) & 15) << 1);
    *(s16x8*)&dst[(size_t)row * CCH + c16 * 8] = *(const s16x8*)&sT[row * CCH + gs * 4];
  }
}

// ---------- finalize + weight prep (proven) ----------
__global__ void stats_finalize2(const float2* __restrict__ partials,
                                const float* __restrict__ gn_w,
                                const float* __restrict__ gn_b,
                                float* __restrict__ scale, float* __restrict__ shift) {
  const int t = threadIdx.x;
  const int b = t >> 3, g = t & 7;
  float s1 = 0.f, s2 = 0.f;
  for (int c = 0; c < 256; ++c) {
    float2 p = partials[(b * 256 + c) * 8 + g];
    s1 += p.x;
    s2 += p.y;
  }
  const float invN = 1.0f / 1048576.0f;
  const float mean = s1 * invN;
  const float var = s2 * invN - mean * mean;
  const float rstd = rsqrtf(var + 1e-5f);
  for (int i = 0; i < 16; ++i) {
    const int c = g * 16 + i;
    const float sc = rstd * gn_w[c];
    scale[b * CCH + c] = sc;
    shift[b * CCH + c] = gn_b[c] - mean * sc;
  }
}

__global__ __launch_bounds__(256) void prep_w2(const float* __restrict__ w2,
                                               ushort* __restrict__ w2b) {
  int i = blockIdx.x * 256 + threadIdx.x;
  float4 a = ((const float4*)w2)[i];
  ushort4 o;
  o.x = f2bf(a.x); o.y = f2bf(a.y); o.z = f2bf(a.z); o.w = f2bf(a.w);
  ((ushort4*)w2b)[i] = o;
}

__global__ __launch_bounds__(128) void fold_w1(const float* __restrict__ w1,
                                               const float* __restrict__ b1,
                                               const float* __restrict__ scale,
                                               const float* __restrict__ shift,
                                               ushort* __restrict__ W1b,
                                               float* __restrict__ c1) {
  const int b = blockIdx.x >> 7, o = blockIdx.x & 127, c = threadIdx.x;
  const float wv = w1[o * CCH + c];
  W1b[(b << 14) + o * CCH + c] = f2bf(wv * scale[b * CCH + c]);
  float s = wv * shift[b * CCH + c];
#pragma unroll
  for (int off = 32; off > 0; off >>= 1) s += __shfl_down(s, off);
  __shared__ float tmp[2];
  if ((threadIdx.x & 63) == 0) tmp[threadIdx.x >> 6] = s;
  __syncthreads();
  if (threadIdx.x == 0) c1[(b << 7) + o] = tmp[0] + tmp[1] + b1[o];
}

// ---------- pass2: cooperative skeleton + LDS-transposed contiguous output ----------
// 4096 blocks (8 b x 512 tiles of 128 px), 256 thr = 4 waves, 32 KiB LDS.
__global__ __launch_bounds__(256, 4) void mlp_tiled(
    const ushort* __restrict__ xb, const ushort* __restrict__ W1b,
    const ushort* __restrict__ w2b, const float* __restrict__ c1,
    const float* __restrict__ b2, float* __restrict__ out) {
  __shared__ ushort sB[128 * CCH];  // 32 KiB: xn(bf16) -> H(bf16) -> out-tile(fp32)
  float* sF = (float*)sB;           // [64 ch-rows][128 px] fp32 view
  const int t = threadIdx.x;
  const int b = blockIdx.x >> 9;
  const int p0 = (blockIdx.x & 511) << 7;
  const int lane = t & 63;
  const int wv = t >> 6;
  const int fl = lane & 15;
  const int fh = lane >> 4;

  // ---- stage: NHWC bf16 global -> swizzled LDS (pure vector copy) ----
  const ushort* src = xb + ((size_t)((b << 16) + p0)) * CCH;
#pragma unroll
  for (int i = 0; i < 8; ++i) {
    const int u = i * 256 + t;
    const int px = u >> 4;
    const int ch = (u & 15) * 8;
    const s16x8 v = *(const s16x8*)(src + px * CCH + ch);
    *(s16x8*)&sB[swz(px, ch)] = v;
  }
  __syncthreads();

  // ---- GEMM1: H = W1' . x ----
  f32x4 acc[2][8];
#pragma unroll
  for (int f = 0; f < 2; ++f)
#pragma unroll
    for (int j = 0; j < 8; ++j) acc[f][j] = (f32x4){0.f, 0.f, 0.f, 0.f};

  const ushort* w1p = W1b + (b << 14);
#pragma unroll
  for (int k0 = 0; k0 < 128; k0 += 32) {
    const int kb = k0 + fh * 8;
    const s16x8 a0 = *(const s16x8*)(w1p + (wv * 32 + fl) * CCH + kb);
    const s16x8 a1 = *(const s16x8*)(w1p + (wv * 32 + 16 + fl) * CCH + kb);
#pragma unroll
    for (int j = 0; j < 8; ++j) {
      const s16x8 bf = *(const s16x8*)&sB[swz(j * 16 + fl, kb)];
      acc[0][j] = __builtin_amdgcn_mfma_f32_16x16x32_bf16(a0, bf, acc[0][j], 0, 0, 0);
      acc[1][j] = __builtin_amdgcn_mfma_f32_16x16x32_bf16(a1, bf, acc[1][j], 0, 0, 0);
    }
  }
  __syncthreads();

  // ---- writeback: H = relu(acc + c1) -> sB ----
  const float* c1b = c1 + (b << 7);
#pragma unroll
  for (int f = 0; f < 2; ++f) {
    const int ob = wv * 32 + f * 16 + fh * 4;
    const float4 cc = *(const float4*)(c1b + ob);
#pragma unroll
    for (int j = 0; j < 8; ++j) {
      ushort4 pk;
      pk.x = f2bf(fmaxf(acc[f][j][0] + cc.x, 0.f));
      pk.y = f2bf(fmaxf(acc[f][j][1] + cc.y, 0.f));
      pk.z = f2bf(fmaxf(acc[f][j][2] + cc.z, 0.f));
      pk.w = f2bf(fmaxf(acc[f][j][3] + cc.w, 0.f));
      *(ushort4*)&sB[swz(j * 16 + fl, ob)] = pk;
    }
  }
  __syncthreads();

  // ---- GEMM2: ffn = w2 . H ----
  f32x4 acc2[2][8];
#pragma unroll
  for (int f = 0; f < 2; ++f)
#pragma unroll
    for (int j = 0; j < 8; ++j) acc2[f][j] = (f32x4){0.f, 0.f, 0.f, 0.f};

#pragma unroll
  for (int k0 = 0; k0 < 128; k0 += 32) {
    const int kb = k0 + fh * 8;
    const s16x8 a0 = *(const s16x8*)(w2b + (wv * 32 + fl) * CCH + kb);
    const s16x8 a1 = *(const s16x8*)(w2b + (wv * 32 + 16 + fl) * CCH + kb);
#pragma unroll
    for (int j = 0; j < 8; ++j) {
      const s16x8 bf = *(const s16x8*)&sB[swz(j * 16 + fl, kb)];
      acc2[0][j] = __builtin_amdgcn_mfma_f32_16x16x32_bf16(a0, bf, acc2[0][j], 0, 0, 0);
      acc2[1][j] = __builtin_amdgcn_mfma_f32_16x16x32_bf16(a1, bf, acc2[1][j], 0, 0, 0);
    }
  }
  __syncthreads();  // all H reads done; sB is now free for the fp32 out-tile

  // ---- epilogue: out = x + ffn + b2, via LDS transpose -> 512B-contiguous stores ----
  // Wave wv owns sF rows [wv*16, wv*16+16) both rounds: no barriers needed
  // (same-wave LDS ops execute in order).
  const int rowbase = wv * 16;
#pragma unroll
  for (int f = 0; f < 2; ++f) {
    const int ob = wv * 32 + f * 16 + fh * 4;
    const float4 bb = *(const float4*)(b2 + ob);
    // residual frags (L2-hot xb re-read, matches acc2 layout)
    ushort4 rx[8];
#pragma unroll
    for (int j = 0; j < 8; ++j)
      rx[j] = *(const ushort4*)(src + (j * 16 + fl) * CCH + ob);
    // scatter fp32 values into [ch][px] tile
#pragma unroll
    for (int j = 0; j < 8; ++j) {
      const int px = j * 16 + fl;
      const int rb = (rowbase + fh * 4) * 128 + px;
      sF[rb]       = acc2[f][j][0] + bb.x + bf2f(rx[j].x);
      sF[rb + 128] = acc2[f][j][1] + bb.y + bf2f(rx[j].y);
      sF[rb + 256] = acc2[f][j][2] + bb.z + bf2f(rx[j].z);
      sF[rb + 384] = acc2[f][j][3] + bb.w + bf2f(rx[j].w);
    }
    // read rows back uniform-row, store 512B contiguous per instruction
#pragma unroll
    for (int i = 0; i < 16; ++i) {
      const float2 v = *(const float2*)&sF[(rowbase + i) * 128 + lane * 2];
      const int ch = wv * 32 + f * 16 + i;
      *(float2*)(out + (((size_t)(b * CCH + ch)) << 16) + p0 + lane * 2) = v;
    }
  }
}

// ---------- launcher ----------
extern "C" void kernel_launch(void* const* d_in, const int* in_sizes, int n_in,
                              void* d_out, int out_size, void* d_ws, size_t ws_size,
                              hipStream_t stream) {
  const float* x    = (const float*)d_in[0];
  const float* gn_w = (const float*)d_in[1];
  const float* gn_b = (const float*)d_in[2];
  const float* w1   = (const float*)d_in[3];
  const float* b1   = (const float*)d_in[4];
  const float* w2   = (const float*)d_in[5];
  const float* b2   = (const float*)d_in[6];
  float* out = (float*)d_out;
  char* ws = (char*)d_ws;

  const size_t XB_BYTES = (size_t)8 * 65536 * CCH * 2;  // 128 MiB
  ushort* xbuf  = (ushort*)ws;
  float2* parts = (float2*)(ws + XB_BYTES);
  float* scale  = (float*)(ws + XB_BYTES + 131072);
  float* shift  = (float*)(ws + XB_BYTES + 135168);
  ushort* w2b   = (ushort*)(ws + XB_BYTES + 139264);
  ushort* W1b   = (ushort*)(ws + XB_BYTES + 172032);
  float* c1     = (float*)(ws + XB_BYTES + 434176);

  hipLaunchKernelGGL(pass1_stats_tr, dim3(2048), dim3(256), 0, stream, x, xbuf, parts);
  hipLaunchKernelGGL(prep_w2, dim3(16), dim3(256), 0, stream, w2, w2b);
  hipLaunchKernelGGL(stats_finalize2, dim3(1), dim3(64), 0, stream, parts, gn_w, gn_b, scale, shift);
  hipLaunchKernelGGL(fold_w1, dim3(1024), dim3(128), 0, stream, w1, b1, scale, shift, W1b, c1);
  hipLaunchKernelGGL(mlp_tiled, dim3(4096), dim3(256), 0, stream, xbuf, W1b, w2b, c1, b2, out);
}